// Round 11
// baseline (1522.208 us; speedup 1.0000x reference)
//
#include <hip/hip_runtime.h>
#include <math.h>

// ---------------------------------------------------------------------------
// MPNN (NNConv+GRU x3, Set2Set x3, readout).
// R11: R10 k_fused + __launch_bounds__(256,4) (LDS 40448B x4 fits 160KB ->
// 4 blocks/CU), fused setup kernels (gptr+cnt+lin0; h1t+bsplit), k_gru
// re-zeros agg2 (drops 2 memsets). Launches 17 -> 11.
// ---------------------------------------------------------------------------

typedef _Float16 f16x8 __attribute__((ext_vector_type(8)));
typedef float f32x4 __attribute__((ext_vector_type(4)));

#define BFRAG_TOTAL (66 * 4 * 4 * 64 * 8)  // 540672 halves per array
#define EMAXB 384                          // max edges per 64-node block (LDS)
#define SPLITK 4
#define CPS 16                             // chunks per split (64/SPLITK)

// fused setup: [0,NB1) gptr ; [NB1,NB1+NB2) cnt ; rest lin0
__global__ __launch_bounds__(256) void k_setup(
    const int* __restrict__ batch, int* __restrict__ gptr,
    const int* __restrict__ eidx, int* __restrict__ cnt,
    const float* __restrict__ x, const float* __restrict__ lw,
    const float* __restrict__ lb, float* __restrict__ outn, int N, int E,
    int B, int NB1, int NB2) {
  const int bid = blockIdx.x, t = threadIdx.x;
  if (bid < NB1) {
    int n = bid * 256 + t;
    if (n >= N) return;
    int b = batch[n];
    int bp = (n == 0) ? -1 : batch[n - 1];
    for (int g = bp + 1; g <= b; ++g) gptr[g] = n;
    if (n == N - 1) {
      for (int g = b + 1; g <= B; ++g) gptr[g] = N;
    }
  } else if (bid < NB1 + NB2) {
    int e = (bid - NB1) * 256 + t;
    if (e < E) atomicAdd(&cnt[eidx[E + e]], 1);
  } else {
    int gid = (bid - NB1 - NB2) * 256 + t;
    int n = gid >> 6, d = gid & 63;
    if (n >= N) return;
    const float* xr = x + (size_t)n * 11;
    const float* wr = lw + d * 11;
    float acc = lb[d];
#pragma unroll
    for (int f = 0; f < 11; ++f) acc += xr[f] * wr[f];
    outn[(size_t)n * 64 + d] = fmaxf(acc, 0.f);
  }
}

// single-block scan via wave shuffles -> dptr (exclusive CSR pointers)
__global__ __launch_bounds__(1024) void k_scan(const int* __restrict__ cnt,
                                               int* __restrict__ dptr, int N) {
  __shared__ int wsum[16];
  int t = threadIdx.x;
  int lane = t & 63, wid = t >> 6;
  if (t == 0) dptr[0] = 0;
  int running = 0;
  for (int base = 0; base < N; base += 1024) {
    int x = (base + t < N) ? cnt[base + t] : 0;
#pragma unroll
    for (int d = 1; d < 64; d <<= 1) {
      int u = __shfl_up(x, d, 64);
      if (lane >= d) x += u;
    }
    if (lane == 63) wsum[wid] = x;
    __syncthreads();
    if (wid == 0) {
      int y = (lane < 16) ? wsum[lane] : 0;
#pragma unroll
      for (int d = 1; d < 16; d <<= 1) {
        int u = __shfl_up(y, d, 64);
        if (lane >= d) y += u;
      }
      if (lane < 16) wsum[lane] = y;
    }
    __syncthreads();
    int add = running + (wid > 0 ? wsum[wid - 1] : 0);
    if (base + t < N) dptr[base + t + 1] = add + x;
    running += wsum[15];
    __syncthreads();
  }
}

__global__ void k_fill(const int* __restrict__ eidx, const int* __restrict__ dptr,
                       int* __restrict__ fill, int* __restrict__ srcs_s,
                       int* __restrict__ eord, int E) {
  int e = blockIdx.x * 256 + threadIdx.x;
  if (e >= E) return;
  int d = eidx[E + e];
  int pos = dptr[d] + atomicAdd(&fill[d], 1);
  srcs_s[pos] = eidx[e];
  eord[pos] = e;
}

// fused prep: [0,NH) h1t (pre-scaled by 1/deg, k-major pairs); rest bsplit
__global__ __launch_bounds__(256) void k_prep(
    const float* __restrict__ eattr, const int* __restrict__ eord,
    const int* __restrict__ eidx, const int* __restrict__ cnt,
    const float* __restrict__ nn1_w, const float* __restrict__ nn1_b,
    float2* __restrict__ h1p, int E, int Epad, int NH,
    const float* __restrict__ nn2_w, const float* __restrict__ nn2_b,
    const float* __restrict__ root_w, _Float16* __restrict__ Bh,
    _Float16* __restrict__ Bl) {
  __shared__ __align__(16) char smem[32768];
  const int bid = blockIdx.x, t = threadIdx.x;
  if (bid < NH) {
    float* a5 = (float*)smem;        // 128*5
    float* w5 = a5 + 640;            // 128*5
    float* bb = w5 + 640;            // 128
    float* idg = bb + 128;           // 128
    const int p0 = bid * 128;
    for (int idx = t; idx < 640; idx += 256) w5[idx] = nn1_w[idx];
    if (t < 128) bb[t] = nn1_b[t];
    if (t < 128) {
      int pos = p0 + t;
      if (pos < E) {
        int e = eord[pos];
        const float* a = eattr + (size_t)e * 5;
#pragma unroll
        for (int q = 0; q < 5; ++q) a5[t * 5 + q] = a[q];
        int dg = cnt[eidx[E + e]];
        idg[t] = 1.f / (float)(dg > 1 ? dg : 1);
      } else {
#pragma unroll
        for (int q = 0; q < 5; ++q) a5[t * 5 + q] = 0.f;
        idg[t] = 0.f;
      }
    }
    __syncthreads();
    const int pl = t & 127, jh = (t >> 7) * 64;
    const int pos = p0 + pl;
    if (pos >= E) return;
    float a0 = a5[pl * 5 + 0], a1 = a5[pl * 5 + 1], a2 = a5[pl * 5 + 2],
          a3 = a5[pl * 5 + 3], a4 = a5[pl * 5 + 4];
    float inv = idg[pl];
#pragma unroll 8
    for (int jj = 0; jj < 64; jj += 2) {
      int j = jh + jj;
      const float* w0 = &w5[j * 5];
      float v0 = fmaxf(bb[j] + a0 * w0[0] + a1 * w0[1] + a2 * w0[2] +
                           a3 * w0[3] + a4 * w0[4], 0.f);
      const float* w1 = &w5[(j + 1) * 5];
      float v1 = fmaxf(bb[j + 1] + a0 * w1[0] + a1 * w1[1] + a2 * w1[2] +
                           a3 * w1[3] + a4 * w1[4], 0.f);
      h1p[(size_t)(j >> 1) * Epad + pos] = make_float2(v0 * inv, v1 * inv);
    }
  } else {
    float* lds = (float*)smem;  // 8192 floats
    const int kc = bid - NH;
    if (kc < 64) {
      for (int r = t; r < 4096; r += 256) {
        float2 v = *(const float2*)&nn2_w[(size_t)r * 128 + kc * 2];
        lds[r * 2] = v.x;
        lds[r * 2 + 1] = v.y;
      }
    } else if (kc == 64) {
      for (int r = t; r < 4096; r += 256) {
        lds[r * 2] = nn2_b[r];
        lds[r * 2 + 1] = 0.f;
      }
    } else {
      for (int r = t; r < 4096; r += 256) {
        int i = r >> 6, o = r & 63;
        lds[r * 2] = root_w[o * 64 + i];
        lds[r * 2 + 1] = 0.f;
      }
    }
    __syncthreads();
    for (int slot = t; slot < 1024; slot += 256) {
      int lane = slot & 63, c = (slot >> 6) & 3, w = slot >> 8;
      f16x8 ph, pl;
#pragma unroll
      for (int j = 0; j < 8; ++j) {
        int m = w * 32 + ((lane >> 4) << 3) + j;
        int o = c * 16 + (lane & 15);
        int i = m & 63, kl = m >> 6;
        float v = lds[(i * 64 + o) * 2 + kl];
        _Float16 h = (_Float16)v;
        ph[j] = h;
        pl[j] = (_Float16)(v - (float)h);
      }
      size_t base = (((size_t)kc * 4 + w) * 4 + c) * 512 + (size_t)lane * 8;
      *(f16x8*)&Bh[base] = ph;
      *(f16x8*)&Bl[base] = pl;
    }
  }
}

// ---------------- fused NNConv (M=64, LDS A-frags, split-K x4) -------------
__global__ __launch_bounds__(256, 4) void k_fused(
    const float* __restrict__ outn, const float2* __restrict__ h1p,
    const int* __restrict__ dptr, const int* __restrict__ srcs_s,
    const _Float16* __restrict__ Bh, const _Float16* __restrict__ Bl,
    float* __restrict__ agg2, int N, int Epad) {
  __shared__ __align__(16) _Float16 Ah[16 * 64 * 8];  // 16 KB
  __shared__ __align__(16) _Float16 Al[16 * 64 * 8];  // 16 KB
  __shared__ __align__(16) float2 hbuf[2][EMAXB];     // 6 KB
  __shared__ int sSrc[EMAXB];                         // 1.5 KB

  const int t = threadIdx.x;
  const int w = t >> 6, lane = t & 63;
  const int nl = t >> 2;   // builder node (0..63)
  const int iq = t & 3;    // i-quarter (16 cols)
  const int split = blockIdx.y;
  const int n0 = blockIdx.x * 64;
  const int n = n0 + nl;
  const bool nvalid = (n < N);
  const int hi_n = (n0 + 64 > N) ? N : (n0 + 64);
  const int p0b = dptr[n0];
  const int p1b = dptr[hi_n];
  const int EB = p1b - p0b;
  const bool useLds = (EB <= EMAXB);
  int p0 = 0, p1 = 0;
  if (nvalid) { p0 = dptr[n]; p1 = dptr[n + 1]; }
  const float inv = 1.f / (float)((p1 - p0) > 1 ? (p1 - p0) : 1);
  const int rt_b = nl >> 4, nm = nl & 15;
  const int EBs = useLds ? EB : 0;

  // ---- stage src list + first h chunk ----
  for (int idx = t; idx < EBs; idx += 256) sSrc[idx] = srcs_s[p0b + idx];
  {
    const float2* hc = h1p + (size_t)(split * CPS) * Epad;
    for (int idx = t; idx < EBs; idx += 256) hbuf[0][idx] = hc[p0b + idx];
  }
  __syncthreads();

  f32x4 acc[4][4];
#pragma unroll
  for (int a = 0; a < 4; ++a)
#pragma unroll
    for (int c = 0; c < 4; ++c) acc[a][c] = (f32x4)(0.f);

  const int niter = (split < 2) ? (CPS + 1) : CPS;
  int cur = 0;
  for (int cc = 0; cc < niter; ++cc) {
    const int mode = (cc < CPS) ? 0 : ((split == 0) ? 1 : 2);
    const int kc = (cc < CPS) ? (split * CPS + cc) : (64 + split);

    // ---- build this thread's 32 A-values (2 kl x 16 i) ----
    float av0[16], av1[16];
#pragma unroll
    for (int j = 0; j < 16; ++j) { av0[j] = 0.f; av1[j] = 0.f; }

    if (mode == 0) {
      const float2* hc = h1p + (size_t)kc * Epad;
      int pos = p0;
      for (; pos + 2 <= p1; pos += 2) {
        int ea = pos - p0b, eb = ea + 1;
        float2 ha = useLds ? hbuf[cur][ea] : hc[pos];
        float2 hb = useLds ? hbuf[cur][eb] : hc[pos + 1];
        int sa = useLds ? sSrc[ea] : srcs_s[pos];
        int sb = useLds ? sSrc[eb] : srcs_s[pos + 1];
        const float4* pa = (const float4*)(outn + (size_t)sa * 64 + iq * 16);
        const float4* pb = (const float4*)(outn + (size_t)sb * 64 + iq * 16);
        float4 a0 = pa[0], a1 = pa[1], a2 = pa[2], a3 = pa[3];
        float4 b0 = pb[0], b1 = pb[1], b2 = pb[2], b3 = pb[3];
        float sva[16] = {a0.x, a0.y, a0.z, a0.w, a1.x, a1.y, a1.z, a1.w,
                         a2.x, a2.y, a2.z, a2.w, a3.x, a3.y, a3.z, a3.w};
        float svb[16] = {b0.x, b0.y, b0.z, b0.w, b1.x, b1.y, b1.z, b1.w,
                         b2.x, b2.y, b2.z, b2.w, b3.x, b3.y, b3.z, b3.w};
#pragma unroll
        for (int j = 0; j < 16; ++j) {
          av0[j] += ha.x * sva[j] + hb.x * svb[j];
          av1[j] += ha.y * sva[j] + hb.y * svb[j];
        }
      }
      if (pos < p1) {
        int ea = pos - p0b;
        float2 ha = useLds ? hbuf[cur][ea] : hc[pos];
        int sa = useLds ? sSrc[ea] : srcs_s[pos];
        const float4* pa = (const float4*)(outn + (size_t)sa * 64 + iq * 16);
        float4 a0 = pa[0], a1 = pa[1], a2 = pa[2], a3 = pa[3];
        float sva[16] = {a0.x, a0.y, a0.z, a0.w, a1.x, a1.y, a1.z, a1.w,
                         a2.x, a2.y, a2.z, a2.w, a3.x, a3.y, a3.z, a3.w};
#pragma unroll
        for (int j = 0; j < 16; ++j) {
          av0[j] += ha.x * sva[j];
          av1[j] += ha.y * sva[j];
        }
      }
    } else if (mode == 1) {  // bias chunk: A[n] = inv * sum_e s[src]
      for (int pos = p0; pos < p1; ++pos) {
        int src = useLds ? sSrc[pos - p0b] : srcs_s[pos];
        const float4* sp = (const float4*)(outn + (size_t)src * 64 + iq * 16);
        float4 s0 = sp[0], s1 = sp[1], s2 = sp[2], s3 = sp[3];
        float sv[16] = {s0.x, s0.y, s0.z, s0.w, s1.x, s1.y, s1.z, s1.w,
                        s2.x, s2.y, s2.z, s2.w, s3.x, s3.y, s3.z, s3.w};
#pragma unroll
        for (int j = 0; j < 16; ++j) av0[j] += sv[j];
      }
#pragma unroll
      for (int j = 0; j < 16; ++j) av0[j] *= inv;
    } else {  // root chunk: A[n] = outn[n]
      if (nvalid) {
        const float4* sp = (const float4*)(outn + (size_t)n * 64 + iq * 16);
        float4 s0 = sp[0], s1 = sp[1], s2 = sp[2], s3 = sp[3];
        float sv[16] = {s0.x, s0.y, s0.z, s0.w, s1.x, s1.y, s1.z, s1.w,
                        s2.x, s2.y, s2.z, s2.w, s3.x, s3.y, s3.z, s3.w};
#pragma unroll
        for (int j = 0; j < 16; ++j) av0[j] = sv[j];
      }
    }

    // ---- split fp16 hi/lo, write A-frag order ----
#pragma unroll
    for (int kl = 0; kl < 2; ++kl) {
      const float* av = kl ? av1 : av0;
      int wb = kl * 2 + (iq >> 1);
#pragma unroll
      for (int g = 0; g < 2; ++g) {
        int q = (iq & 1) * 2 + g;
        int base = ((wb * 4 + rt_b) * 64 + (q << 4) + nm) * 8;
        f16x8 ph, pl;
#pragma unroll
        for (int jj = 0; jj < 8; ++jj) {
          float v = av[g * 8 + jj];
          _Float16 h = (_Float16)v;
          ph[jj] = h;
          pl[jj] = (_Float16)(v - (float)h);
        }
        *(f16x8*)&Ah[base] = ph;
        *(f16x8*)&Al[base] = pl;
      }
    }
    __syncthreads();

    // ---- MFMA (wave w = k-slice) + prefetch next h chunk ----
    f16x8 ah[4], al[4];
#pragma unroll
    for (int rt = 0; rt < 4; ++rt) {
      ah[rt] = *(const f16x8*)&Ah[((w * 4 + rt) * 64 + lane) * 8];
      al[rt] = *(const f16x8*)&Al[((w * 4 + rt) * 64 + lane) * 8];
    }
    if (cc + 1 < CPS) {
      const float2* hc = h1p + (size_t)(split * CPS + cc + 1) * Epad;
      for (int idx = t; idx < EBs; idx += 256) hbuf[cur ^ 1][idx] = hc[p0b + idx];
    }
    size_t bbase = ((size_t)(kc * 4 + w) * 4) * 512;
#pragma unroll
    for (int c = 0; c < 4; ++c) {
      f16x8 bh = *(const f16x8*)&Bh[bbase + c * 512 + lane * 8];
      f16x8 bl = *(const f16x8*)&Bl[bbase + c * 512 + lane * 8];
#pragma unroll
      for (int rt = 0; rt < 4; ++rt) {
        acc[rt][c] = __builtin_amdgcn_mfma_f32_16x16x32_f16(ah[rt], bh, acc[rt][c], 0, 0, 0);
        acc[rt][c] = __builtin_amdgcn_mfma_f32_16x16x32_f16(ah[rt], bl, acc[rt][c], 0, 0, 0);
        acc[rt][c] = __builtin_amdgcn_mfma_f32_16x16x32_f16(al[rt], bh, acc[rt][c], 0, 0, 0);
      }
    }
    __syncthreads();
    if (cc + 1 < CPS) cur ^= 1;
  }

  // ---- epilogue: atomic accumulate (split-K) ----
  const int qrow = (lane >> 4) * 4, col = lane & 15;
#pragma unroll
  for (int rt = 0; rt < 4; ++rt) {
#pragma unroll
    for (int r = 0; r < 4; ++r) {
      int nn = n0 + rt * 16 + qrow + r;
      if (nn < N) {
        float* ap = agg2 + (size_t)nn * 64 + col;
#pragma unroll
        for (int c = 0; c < 4; ++c) atomicAdd(ap + c * 16, acc[rt][c][r]);
      }
    }
  }
}

// GRU step (16 nodes/block, 4 per wave); re-zeros agg2 for next iteration
__global__ __launch_bounds__(256) void k_gru(
    float* __restrict__ agg2, const float* __restrict__ conv_b,
    const float* __restrict__ gw_ih, const float* __restrict__ gw_hh,
    const float* __restrict__ gb_ih, const float* __restrict__ gb_hh,
    float* __restrict__ outn, int N) {
  __shared__ float wT[32 * 385];
  const int t = threadIdx.x;
  const int wv = t >> 6, d = t & 63;
  const int nbase = blockIdx.x * 16 + wv * 4;
  float m_d[4], h_d[4];
  bool act[4];
#pragma unroll
  for (int j = 0; j < 4; ++j) {
    int n = nbase + j;
    act[j] = (n < N);
    if (act[j]) {
      size_t o = (size_t)n * 64 + d;
      m_d[j] = fmaxf(agg2[o] + conv_b[d], 0.f);
      h_d[j] = outn[o];
      agg2[o] = 0.f;  // re-zero for next conv iteration
    } else {
      m_d[j] = 0.f;
      h_d[j] = 0.f;
    }
  }
  float ir[4] = {0, 0, 0, 0}, iz[4] = {0, 0, 0, 0}, in_[4] = {0, 0, 0, 0};
  float hr[4] = {0, 0, 0, 0}, hz[4] = {0, 0, 0, 0}, hn[4] = {0, 0, 0, 0};
  for (int half = 0; half < 2; ++half) {
    __syncthreads();
    for (int idx = t; idx < 192 * 32; idx += 256) {
      int g = idx >> 5, kl = idx & 31;
      wT[kl * 385 + g] = gw_ih[g * 64 + half * 32 + kl];
      wT[kl * 385 + 192 + g] = gw_hh[g * 64 + half * 32 + kl];
    }
    __syncthreads();
#pragma unroll
    for (int kl = 0; kl < 32; ++kl) {
      int k = half * 32 + kl;
      const float* row = &wT[kl * 385];
      float r0 = row[d], r1 = row[64 + d], r2 = row[128 + d];
      float r3 = row[192 + d], r4 = row[256 + d], r5 = row[320 + d];
#pragma unroll
      for (int j = 0; j < 4; ++j) {
        float mk = __shfl(m_d[j], k);
        float hk = __shfl(h_d[j], k);
        ir[j] += r0 * mk;
        iz[j] += r1 * mk;
        in_[j] += r2 * mk;
        hr[j] += r3 * hk;
        hz[j] += r4 * hk;
        hn[j] += r5 * hk;
      }
    }
  }
#pragma unroll
  for (int j = 0; j < 4; ++j) {
    if (act[j]) {
      int n = nbase + j;
      float r = 1.f / (1.f + expf(-(ir[j] + gb_ih[d] + hr[j] + gb_hh[d])));
      float z = 1.f / (1.f + expf(-(iz[j] + gb_ih[64 + d] + hz[j] + gb_hh[64 + d])));
      float nn = tanhf(in_[j] + gb_ih[128 + d] + r * (hn[j] + gb_hh[128 + d]));
      outn[(size_t)n * 64 + d] = (1.f - z) * nn + z * h_d[j];
    }
  }
}

// ---------------- fused Set2Set (3 steps) + readout, one block per graph ---
__global__ __launch_bounds__(256) void k_s2s(
    const float* __restrict__ outn, const int* __restrict__ gptr,
    const float* __restrict__ w_ih, const float* __restrict__ w_hh,
    const float* __restrict__ b_ih, const float* __restrict__ b_hh,
    const float* __restrict__ w1, const float* __restrict__ b1,
    const float* __restrict__ w2, const float* __restrict__ b2,
    float* __restrict__ y) {
  __shared__ float q[128];
  __shared__ float hsL[64];
  __shared__ float csL[64];
  __shared__ float gate[256];
  __shared__ float red[4][66];  // per-wave: m, den, racc[64]
  const int b = blockIdx.x, t = threadIdx.x;
  const int wv = t >> 6, d = t & 63;
  const int n0 = gptr[b], n1 = gptr[b + 1];
  if (t < 128) q[t] = 0.f;
  if (t < 64) { hsL[t] = 0.f; csL[t] = 0.f; }
  __syncthreads();

  for (int step = 0; step < 3; ++step) {
    float acc = b_ih[t] + b_hh[t];
    const float* wi = w_ih + t * 128;
    const float* wh = w_hh + t * 64;
#pragma unroll 4
    for (int k = 0; k < 128; ++k) acc += wi[k] * q[k];
#pragma unroll 4
    for (int k = 0; k < 64; ++k) acc += wh[k] * hsL[k];
    gate[t] = acc;
    __syncthreads();
    if (t < 64) {
      float ig = gate[t], fg = gate[64 + t], gg = gate[128 + t],
            og = gate[192 + t];
      float c = csL[t];
      float si = 1.f / (1.f + expf(-ig));
      float sf = 1.f / (1.f + expf(-fg));
      float so = 1.f / (1.f + expf(-og));
      float cn = sf * c + si * tanhf(gg);
      csL[t] = cn;
      hsL[t] = so * tanhf(cn);
    }
    __syncthreads();

    float qd = hsL[d];
    float mx = -3.4e38f, den = 0.f, racc = 0.f;
    for (int nn = n0 + wv; nn < n1; nn += 4) {
      float od = outn[(size_t)nn * 64 + d];
      float v = od * qd;
      for (int s = 32; s > 0; s >>= 1) v += __shfl_xor(v, s);
      float mnew = fmaxf(mx, v);
      float scale = expf(mx - mnew);
      float a = expf(v - mnew);
      den = den * scale + a;
      racc = racc * scale + a * od;
      mx = mnew;
    }
    if (d == 0) { red[wv][0] = mx; red[wv][1] = den; }
    red[wv][2 + d] = racc;
    __syncthreads();
    if (t < 64) {
      float M = fmaxf(fmaxf(red[0][0], red[1][0]), fmaxf(red[2][0], red[3][0]));
      float dd = 0.f, rr = 0.f;
#pragma unroll
      for (int ww = 0; ww < 4; ++ww) {
        float sc = expf(red[ww][0] - M);
        dd += red[ww][1] * sc;
        rr += red[ww][2 + t] * sc;
      }
      float r = (dd > 0.f) ? rr / dd : 0.f;
      q[t] = hsL[t];
      q[64 + t] = r;
    }
    __syncthreads();
  }

  if (t < 64) {
    float acc = b1[t];
    const float* wr = w1 + t * 128;
#pragma unroll 4
    for (int k = 0; k < 128; ++k) acc += wr[k] * q[k];
    acc = fmaxf(acc, 0.f) * w2[t];
    for (int s = 32; s > 0; s >>= 1) acc += __shfl_xor(acc, s);
    if (t == 0) y[b] = acc + b2[0];
  }
}

extern "C" void kernel_launch(void* const* d_in, const int* in_sizes, int n_in,
                              void* d_out, int out_size, void* d_ws,
                              size_t ws_size, hipStream_t stream) {
  (void)n_in; (void)out_size; (void)ws_size;
  const float* x      = (const float*)d_in[0];
  const int*   eidx   = (const int*)d_in[1];
  const float* eattr  = (const float*)d_in[2];
  const int*   batch  = (const int*)d_in[3];
  const float* lin0_w = (const float*)d_in[4];
  const float* lin0_b = (const float*)d_in[5];
  const float* nn1_w  = (const float*)d_in[6];
  const float* nn1_b  = (const float*)d_in[7];
  const float* nn2_w  = (const float*)d_in[8];
  const float* nn2_b  = (const float*)d_in[9];
  const float* root_w = (const float*)d_in[10];
  const float* conv_b = (const float*)d_in[11];
  const float* gw_ih  = (const float*)d_in[12];
  const float* gw_hh  = (const float*)d_in[13];
  const float* gb_ih  = (const float*)d_in[14];
  const float* gb_hh  = (const float*)d_in[15];
  const float* lw_ih  = (const float*)d_in[16];
  const float* lw_hh  = (const float*)d_in[17];
  const float* lb_ih  = (const float*)d_in[18];
  const float* lb_hh  = (const float*)d_in[19];
  const float* lin1_w = (const float*)d_in[20];
  const float* lin1_b = (const float*)d_in[21];
  const float* lin2_w = (const float*)d_in[22];
  const float* lin2_b = (const float*)d_in[23];

  const int N = in_sizes[0] / 11;
  const int E = in_sizes[1] / 2;
  const int B = 512;
  const int Epad = (E + 127) & ~127;

  size_t off = 0;
  auto bump = [&](size_t bytes) {
    size_t o = off;
    off += (bytes + 255) & ~(size_t)255;
    return o;
  };
  char* base = (char*)d_ws;
  float*     outn   = (float*)(base + bump((size_t)N * 64 * 4));
  float*     agg2   = (float*)(base + bump((size_t)N * 64 * 4));
  float2*    h1p    = (float2*)(base + bump((size_t)64 * Epad * 8));
  _Float16*  Bh     = (_Float16*)(base + bump((size_t)BFRAG_TOTAL * 2));
  _Float16*  Bl     = (_Float16*)(base + bump((size_t)BFRAG_TOTAL * 2));
  int*       cnt    = (int*)(base + bump((size_t)2 * N * 4));  // cnt + fill
  int*       fill   = cnt + N;
  int*       dptr   = (int*)(base + bump((size_t)(N + 1) * 4));
  int*       srcs_s = (int*)(base + bump((size_t)E * 4));
  int*       eord   = (int*)(base + bump((size_t)E * 4));
  int*       gptr   = (int*)(base + bump((size_t)(B + 1) * 4));

  hipMemsetAsync(cnt, 0, (size_t)2 * N * 4, stream);

  const int NB1 = (N + 255) / 256;
  const int NB2 = (E + 255) / 256;
  const int NB3 = (N * 64 + 255) / 256;
  k_setup<<<NB1 + NB2 + NB3, 256, 0, stream>>>(batch, gptr, eidx, cnt, x,
                                               lin0_w, lin0_b, outn, N, E, B,
                                               NB1, NB2);
  k_scan<<<1, 1024, 0, stream>>>(cnt, dptr, N);
  k_fill<<<(E + 255) / 256, 256, 0, stream>>>(eidx, dptr, fill, srcs_s, eord, E);
  const int NH = (E + 127) / 128;
  k_prep<<<NH + 66, 256, 0, stream>>>(eattr, eord, eidx, cnt, nn1_w, nn1_b,
                                      h1p, E, Epad, NH, nn2_w, nn2_b, root_w,
                                      Bh, Bl);
  hipMemsetAsync(agg2, 0, (size_t)N * 64 * 4, stream);

  const int NBLK = (N + 63) / 64;
  for (int it = 0; it < 3; ++it) {
    k_fused<<<dim3(NBLK, SPLITK), 256, 0, stream>>>(outn, h1p, dptr, srcs_s, Bh,
                                                    Bl, agg2, N, Epad);
    k_gru<<<(N + 15) / 16, 256, 0, stream>>>(agg2, conv_b, gw_ih, gw_hh, gb_ih,
                                             gb_hh, outn, N);
  }

  k_s2s<<<B, 256, 0, stream>>>(outn, gptr, lw_ih, lw_hh, lb_ih, lb_hh, lin1_w,
                               lin1_b, lin2_w, lin2_b, (float*)d_out);
}